// Round 1
// baseline (115.460 us; speedup 1.0000x reference)
//
#include <hip/hip_runtime.h>
#include <hip/hip_bf16.h>

// MetricLearningLoss: N=4096 points, D=1024, fp32 inputs, int labels.
// loss = sum_{i<j} [ same: -coeff*log(a)+0.5a ; diff: coeff*log(b)-0.5b ]
//   a = d2/327.68, b = d2/8192, coeff = 2047, d2 = ||xi-xj||^2 via gram.
// Strategy: bf16 MFMA gram on upper-triangular 128x128 tile pairs, fused
// epilogue (log + select + masked triangular sum), atomicAdd scalar.

#define NPTS 4096
#define DIM  1024
#define TILE 128
#define BK   32
#define NT   (NPTS / TILE)            // 32
#define NPAIR (NT * (NT + 1) / 2)     // 528

typedef __attribute__((ext_vector_type(4))) float f32x4;
typedef __attribute__((ext_vector_type(8))) short bf16x8;

__device__ __forceinline__ ushort f2bf(float x) {
    __hip_bfloat16 h = __float2bfloat16(x);
    return *reinterpret_cast<ushort*>(&h);
}

__device__ __forceinline__ void gload_lds16(const ushort* g, ushort* l) {
    __builtin_amdgcn_global_load_lds(
        (const __attribute__((address_space(1))) void*)g,
        (__attribute__((address_space(3))) void*)l, 16, 0, 0);
}

// Kernel 1: fp32 -> bf16 conversion + per-row sum of squares (fp32).
__global__ __launch_bounds__(256) void prep_kernel(const float* __restrict__ X,
                                                   ushort* __restrict__ Xb,
                                                   float* __restrict__ sq) {
    const int row = blockIdx.x;
    const int t = threadIdx.x;
    const float4 v = reinterpret_cast<const float4*>(X + (size_t)row * DIM)[t];
    float s = v.x * v.x + v.y * v.y + v.z * v.z + v.w * v.w;
    ushort4 o;
    o.x = f2bf(v.x); o.y = f2bf(v.y); o.z = f2bf(v.z); o.w = f2bf(v.w);
    reinterpret_cast<ushort4*>(Xb + (size_t)row * DIM)[t] = o;
#pragma unroll
    for (int off = 32; off > 0; off >>= 1) s += __shfl_down(s, off);
    __shared__ float ws[4];
    const int lane = t & 63, w = t >> 6;
    if (lane == 0) ws[w] = s;
    __syncthreads();
    if (t == 0) sq[row] = ws[0] + ws[1] + ws[2] + ws[3];
}

// Kernel 2: per upper-triangular tile pair (ti<=tj): gram tile via MFMA,
// fused loss epilogue, block reduce, atomicAdd.
__global__ __launch_bounds__(256) void loss_kernel(const ushort* __restrict__ Xb,
                                                   const float* __restrict__ sq,
                                                   const int* __restrict__ labels,
                                                   float* __restrict__ out) {
    __shared__ ushort At[TILE * BK];   // [128][32] bf16, 8 KB
    __shared__ ushort Bt[TILE * BK];

    // decode upper-triangular (ti, tj), ti <= tj
    int b = blockIdx.x;
    int ti = 0, rem = b;
    while (rem >= NT - ti) { rem -= NT - ti; ++ti; }
    const int tj = ti + rem;

    const int t = threadIdx.x;
    const int lane = t & 63;
    const int wave = t >> 6;
    const int wr = wave >> 1, wc = wave & 1;   // wave -> 64x64 quadrant

    // staging: thread t covers tile row (t>>2), 16B chunk (t&3); two instrs
    // per tile (rows 0..63, 64..127). LDS dest = wave-uniform base + lane*16B.
    const int r0 = t >> 2;
    const int cg = t & 3;
    const ushort* gA0 = Xb + (size_t)(ti * TILE + r0) * DIM + cg * 8;
    const ushort* gA1 = gA0 + (size_t)64 * DIM;
    const ushort* gB0 = Xb + (size_t)(tj * TILE + r0) * DIM + cg * 8;
    const ushort* gB1 = gB0 + (size_t)64 * DIM;
    ushort* lA0 = At + (size_t)(t & ~63) * 8;  // = wave*1024 bytes
    ushort* lA1 = lA0 + 2048;                  // +4096 bytes
    ushort* lB0 = Bt + (size_t)(t & ~63) * 8;
    ushort* lB1 = lB0 + 2048;

    const int fr = lane & 15;    // fragment row (A) / col (B)
    const int kg = lane >> 4;    // k-group (8 contiguous k each)
    const ushort* laBase = At + (wr * 64 + fr) * BK + kg * 8;
    const ushort* lbBase = Bt + (wc * 64 + fr) * BK + kg * 8;

    f32x4 acc[4][4] = {};

    for (int kt = 0; kt < DIM / BK; ++kt) {
        const int ko = kt * BK;
        gload_lds16(gA0 + ko, lA0);
        gload_lds16(gA1 + ko, lA1);
        gload_lds16(gB0 + ko, lB0);
        gload_lds16(gB1 + ko, lB1);
        __syncthreads();   // vmcnt(0) drain + barrier: tiles ready
        bf16x8 af[4], bf[4];
#pragma unroll
        for (int m = 0; m < 4; ++m)
            af[m] = *(const bf16x8*)(laBase + m * 16 * BK);
#pragma unroll
        for (int n = 0; n < 4; ++n)
            bf[n] = *(const bf16x8*)(lbBase + n * 16 * BK);
#pragma unroll
        for (int m = 0; m < 4; ++m)
#pragma unroll
            for (int n = 0; n < 4; ++n)
                acc[m][n] = __builtin_amdgcn_mfma_f32_16x16x32_bf16(
                    af[m], bf[n], acc[m][n], 0, 0, 0);
        __syncthreads();   // all reads done before next staging
    }

    // epilogue: C/D layout col = lane&15, row = (lane>>4)*4 + reg  [m89/m91]
    int gi[16]; float sqi[16]; int li[16];
#pragma unroll
    for (int m = 0; m < 4; ++m)
#pragma unroll
        for (int q = 0; q < 4; ++q) {
            const int i = ti * TILE + wr * 64 + m * 16 + kg * 4 + q;
            gi[m * 4 + q] = i;
            sqi[m * 4 + q] = sq[i];
            li[m * 4 + q] = labels[i];
        }
    int gj[4]; float sqj[4]; int lj[4];
#pragma unroll
    for (int n = 0; n < 4; ++n) {
        const int j = tj * TILE + wc * 64 + n * 16 + fr;
        gj[n] = j;
        sqj[n] = sq[j];
        lj[n] = labels[j];
    }

    const float coeff = 2047.0f;                       // N/2 - 1
    const float inva = 1.0f / (2.0f * 4096.0f * 0.04f); // 1/327.68
    const float invb = 1.0f / (2.0f * 4096.0f);         // 1/8192
    const float lc1 = -5.792037522411088f;              // ln(inva)
    const float lc2 = -9.010913347279289f;              // ln(invb)
    const bool diag = (ti == tj);

    float lsum = 0.0f;
#pragma unroll
    for (int m = 0; m < 4; ++m)
#pragma unroll
        for (int n = 0; n < 4; ++n)
#pragma unroll
            for (int q = 0; q < 4; ++q) {
                const int ii = m * 4 + q;
                const float g = acc[m][n][q];
                float d2 = sqi[ii] + sqj[n] - 2.0f * g;
                d2 = fmaxf(d2, 1e-12f);
                const bool same = (li[ii] == lj[n]);
                const float inv = same ? inva : invb;
                const float lc  = same ? lc1 : lc2;
                const float sgn = same ? -1.0f : 1.0f;
                const float p = sgn * (coeff * (logf(d2) + lc) - 0.5f * d2 * inv);
                const bool inc = diag ? (gi[ii] < gj[n]) : true;
                lsum += inc ? p : 0.0f;
            }

    // block reduce + one atomic per block
#pragma unroll
    for (int off = 32; off > 0; off >>= 1) lsum += __shfl_down(lsum, off);
    __shared__ float bsum[4];
    if (lane == 0) bsum[wave] = lsum;
    __syncthreads();
    if (t == 0) atomicAdd(out, bsum[0] + bsum[1] + bsum[2] + bsum[3]);
}

extern "C" void kernel_launch(void* const* d_in, const int* in_sizes, int n_in,
                              void* d_out, int out_size, void* d_ws, size_t ws_size,
                              hipStream_t stream) {
    const float* X = (const float*)d_in[0];
    const int* labels = (const int*)d_in[1];
    float* out = (float*)d_out;
    ushort* Xb = (ushort*)d_ws;                                   // 8 MB bf16
    float* sq = (float*)((char*)d_ws + (size_t)NPTS * DIM * 2);   // 16 KB

    hipMemsetAsync(d_out, 0, sizeof(float), stream);
    prep_kernel<<<NPTS, 256, 0, stream>>>(X, Xb, sq);
    loss_kernel<<<NPAIR, 256, 0, stream>>>(Xb, sq, labels, out);
}

// Round 2
// 103.224 us; speedup vs baseline: 1.1185x; 1.1185x over previous
//
#include <hip/hip_runtime.h>
#include <hip/hip_bf16.h>

// MetricLearningLoss: N=4096 points, D=1024, fp32 inputs, int labels.
// loss = sum_{i<j} [ same: -coeff*log(a)+0.5a ; diff: coeff*log(b)-0.5b ]
//   a = d2/327.68, b = d2/8192, coeff = 2047, d2 = ||xi-xj||^2 via gram.
// R2: 8 waves/block, BK=64, double-buffered prefetch (T3-min), T2 XOR
// swizzle (pre-swizzled global source, rule #21), T1 XCD swizzle.

#define NPTS 4096
#define DIM  1024
#define TILE 128
#define BK   64
#define KSTEPS (DIM / BK)             // 16
#define NT   (NPTS / TILE)            // 32
#define NPAIR (NT * (NT + 1) / 2)     // 528 = 8 * 66
#define THREADS 512

typedef __attribute__((ext_vector_type(4))) float f32x4;
typedef __attribute__((ext_vector_type(8))) short bf16x8;

__device__ __forceinline__ ushort f2bf(float x) {
    __hip_bfloat16 h = __float2bfloat16(x);
    return *reinterpret_cast<ushort*>(&h);
}

__device__ __forceinline__ void gload_lds16(const ushort* g, ushort* l) {
    __builtin_amdgcn_global_load_lds(
        (const __attribute__((address_space(1))) void*)g,
        (__attribute__((address_space(3))) void*)l, 16, 0, 0);
}

// Kernel 1: fp32 -> bf16 conversion + per-row sum of squares (fp32).
__global__ __launch_bounds__(256) void prep_kernel(const float* __restrict__ X,
                                                   ushort* __restrict__ Xb,
                                                   float* __restrict__ sq) {
    const int row = blockIdx.x;
    const int t = threadIdx.x;
    const float4 v = reinterpret_cast<const float4*>(X + (size_t)row * DIM)[t];
    float s = v.x * v.x + v.y * v.y + v.z * v.z + v.w * v.w;
    ushort4 o;
    o.x = f2bf(v.x); o.y = f2bf(v.y); o.z = f2bf(v.z); o.w = f2bf(v.w);
    reinterpret_cast<ushort4*>(Xb + (size_t)row * DIM)[t] = o;
#pragma unroll
    for (int off = 32; off > 0; off >>= 1) s += __shfl_down(s, off);
    __shared__ float ws[4];
    const int lane = t & 63, w = t >> 6;
    if (lane == 0) ws[w] = s;
    __syncthreads();
    if (t == 0) sq[row] = ws[0] + ws[1] + ws[2] + ws[3];
}

// Kernel 2: per upper-triangular 128x128 tile pair (ti<=tj): gram via MFMA,
// fused loss epilogue, block reduce, atomicAdd.
__global__ __launch_bounds__(THREADS, 4) void loss_kernel(const ushort* __restrict__ Xb,
                                                          const float* __restrict__ sq,
                                                          const int* __restrict__ labels,
                                                          float* __restrict__ out) {
    __shared__ ushort At[2][TILE * BK];   // 2 x 16 KB
    __shared__ ushort Bt[2][TILE * BK];   // 2 x 16 KB
    __shared__ float bsum[8];

    // T1: bijective XCD swizzle (528 % 8 == 0): same-XCD blocks get
    // consecutive tile ids -> shared A row-panels stay L2-resident.
    const int b0 = blockIdx.x;
    const int b = (b0 & 7) * (NPAIR / 8) + (b0 >> 3);

    // decode upper-triangular (ti, tj), ti <= tj
    int ti = 0, rem = b;
    while (rem >= NT - ti) { rem -= NT - ti; ++ti; }
    const int tj = ti + rem;

    const int t = threadIdx.x;
    const int lane = t & 63;
    const int wave = t >> 6;      // 0..7
    const int wr = wave >> 1;     // 0..3 : 32-row band of A
    const int wc = wave & 1;      // 0..1 : 64-col band of B
    const int fr = lane & 15;
    const int kg = lane >> 4;

    // Staging: thread t writes linear LDS bytes [t*16, t*16+16) (+8KB for
    // second 64-row half). Linear position (row sr, chunk t&7) must hold
    // global chunk (t&7)^(sr&7)  [T2 swizzle via pre-swizzled source].
    const int sr = t >> 3;                       // 0..63
    const int sc = ((t & 7) ^ (sr & 7)) * 8;     // swizzled source chunk (elems)
    const ushort* gA = Xb + (size_t)(ti * TILE + sr) * DIM + sc;
    const ushort* gB = Xb + (size_t)(tj * TILE + sr) * DIM + sc;

    f32x4 acc[2][4] = {};

#define STAGE(buf, kt) do {                                        \
        const int _ko = (kt) * BK;                                 \
        gload_lds16(gA + _ko,                 &At[buf][t * 8]);            \
        gload_lds16(gA + (size_t)64 * DIM + _ko, &At[buf][t * 8 + 4096]);  \
        gload_lds16(gB + _ko,                 &Bt[buf][t * 8]);            \
        gload_lds16(gB + (size_t)64 * DIM + _ko, &Bt[buf][t * 8 + 4096]);  \
    } while (0)

    int cur = 0;
    STAGE(0, 0);
    __syncthreads();   // drain prologue stage

    for (int kt = 0; kt < KSTEPS; ++kt) {
        if (kt + 1 < KSTEPS) STAGE(cur ^ 1, kt + 1);   // prefetch next tile
        // compute from buf[cur]; swizzled read: chunk = (kk*4+kg) ^ (fr&7)
#pragma unroll
        for (int kk = 0; kk < 2; ++kk) {
            const int swz = (((kk << 2) | kg) ^ (fr & 7)) * 8;
            bf16x8 af[2], bv[4];
#pragma unroll
            for (int m = 0; m < 2; ++m)
                af[m] = *(const bf16x8*)&At[cur][(wr * 32 + m * 16 + fr) * BK + swz];
#pragma unroll
            for (int n = 0; n < 4; ++n)
                bv[n] = *(const bf16x8*)&Bt[cur][(wc * 64 + n * 16 + fr) * BK + swz];
#pragma unroll
            for (int m = 0; m < 2; ++m)
#pragma unroll
                for (int n = 0; n < 4; ++n)
                    acc[m][n] = __builtin_amdgcn_mfma_f32_16x16x32_bf16(
                        af[m], bv[n], acc[m][n], 0, 0, 0);
        }
        __syncthreads();   // prefetch complete + all reads of cur done
        cur ^= 1;
    }
#undef STAGE

    // epilogue: C/D layout col = lane&15 (=fr), row = kg*4 + q  [m89/m91]
    int gi[8]; float sqi[8]; int li[8];
#pragma unroll
    for (int m = 0; m < 2; ++m)
#pragma unroll
        for (int q = 0; q < 4; ++q) {
            const int i = ti * TILE + wr * 32 + m * 16 + kg * 4 + q;
            gi[m * 4 + q] = i;
            sqi[m * 4 + q] = sq[i];
            li[m * 4 + q] = labels[i];
        }
    int gj[4]; float sqj[4]; int lj[4];
#pragma unroll
    for (int n = 0; n < 4; ++n) {
        const int j = tj * TILE + wc * 64 + n * 16 + fr;
        gj[n] = j;
        sqj[n] = sq[j];
        lj[n] = labels[j];
    }

    const float coeff = 2047.0f;                        // N/2 - 1
    const float inva = 1.0f / (2.0f * 4096.0f * 0.04f); // 1/327.68
    const float invb = 1.0f / (2.0f * 4096.0f);         // 1/8192
    const float lc1 = -5.792037522411088f;              // ln(inva)
    const float lc2 = -9.010913347279289f;              // ln(invb)
    const bool diag = (ti == tj);

    float lsum = 0.0f;
#pragma unroll
    for (int m = 0; m < 2; ++m)
#pragma unroll
        for (int n = 0; n < 4; ++n)
#pragma unroll
            for (int q = 0; q < 4; ++q) {
                const int ii = m * 4 + q;
                const float g = acc[m][n][q];
                float d2 = sqi[ii] + sqj[n] - 2.0f * g;
                d2 = fmaxf(d2, 1e-12f);
                const bool same = (li[ii] == lj[n]);
                const float inv = same ? inva : invb;
                const float lc  = same ? lc1 : lc2;
                const float sgn = same ? -1.0f : 1.0f;
                const float p = sgn * (coeff * (logf(d2) + lc) - 0.5f * d2 * inv);
                const bool inc = diag ? (gi[ii] < gj[n]) : true;
                lsum += inc ? p : 0.0f;
            }

    // block reduce + one atomic per block
#pragma unroll
    for (int off = 32; off > 0; off >>= 1) lsum += __shfl_down(lsum, off);
    if (lane == 0) bsum[wave] = lsum;
    __syncthreads();
    if (t == 0) {
        float s = 0.0f;
#pragma unroll
        for (int w = 0; w < 8; ++w) s += bsum[w];
        atomicAdd(out, s);
    }
}

extern "C" void kernel_launch(void* const* d_in, const int* in_sizes, int n_in,
                              void* d_out, int out_size, void* d_ws, size_t ws_size,
                              hipStream_t stream) {
    const float* X = (const float*)d_in[0];
    const int* labels = (const int*)d_in[1];
    float* out = (float*)d_out;
    ushort* Xb = (ushort*)d_ws;                                   // 8 MB bf16
    float* sq = (float*)((char*)d_ws + (size_t)NPTS * DIM * 2);   // 16 KB

    hipMemsetAsync(d_out, 0, sizeof(float), stream);
    prep_kernel<<<NPTS, 256, 0, stream>>>(X, Xb, sq);
    loss_kernel<<<NPAIR, THREADS, 0, stream>>>(Xb, sq, labels, out);
}

// Round 3
// 101.246 us; speedup vs baseline: 1.1404x; 1.0195x over previous
//
#include <hip/hip_runtime.h>
#include <hip/hip_bf16.h>

// MetricLearningLoss: N=4096 points, D=1024, fp32 inputs, int labels.
// loss = sum_{i<j} [ same: -coeff*log(a)+0.5a ; diff: coeff*log(b)-0.5b ]
// R3: m97 geometry (128^2 tile, 4 waves x 64x64, BK=32, 0.5 ds-reads/MFMA),
// dbuf prefetch, BK32 swizzle (chunk ^= (row>>1)&3), 3 blocks/CU residency,
// diag-wave skip, __logf epilogue, T1 XCD swizzle.

#define NPTS 4096
#define DIM  1024
#define TILE 128
#define BK   32
#define KSTEPS (DIM / BK)             // 32
#define NT   (NPTS / TILE)            // 32
#define NPAIR (NT * (NT + 1) / 2)     // 528 = 8 * 66
#define THREADS 256

typedef __attribute__((ext_vector_type(4))) float f32x4;
typedef __attribute__((ext_vector_type(8))) short bf16x8;

__device__ __forceinline__ ushort f2bf(float x) {
    __hip_bfloat16 h = __float2bfloat16(x);
    return *reinterpret_cast<ushort*>(&h);
}

__device__ __forceinline__ void gload_lds16(const ushort* g, ushort* l) {
    __builtin_amdgcn_global_load_lds(
        (const __attribute__((address_space(1))) void*)g,
        (__attribute__((address_space(3))) void*)l, 16, 0, 0);
}

// Kernel 1: fp32 -> bf16 conversion + per-row sum of squares (fp32).
__global__ __launch_bounds__(256) void prep_kernel(const float* __restrict__ X,
                                                   ushort* __restrict__ Xb,
                                                   float* __restrict__ sq) {
    const int row = blockIdx.x;
    const int t = threadIdx.x;
    const float4 v = reinterpret_cast<const float4*>(X + (size_t)row * DIM)[t];
    float s = v.x * v.x + v.y * v.y + v.z * v.z + v.w * v.w;
    ushort4 o;
    o.x = f2bf(v.x); o.y = f2bf(v.y); o.z = f2bf(v.z); o.w = f2bf(v.w);
    reinterpret_cast<ushort4*>(Xb + (size_t)row * DIM)[t] = o;
#pragma unroll
    for (int off = 32; off > 0; off >>= 1) s += __shfl_down(s, off);
    __shared__ float ws[4];
    const int lane = t & 63, w = t >> 6;
    if (lane == 0) ws[w] = s;
    __syncthreads();
    if (t == 0) sq[row] = ws[0] + ws[1] + ws[2] + ws[3];
}

// Kernel 2: per upper-triangular 128x128 tile pair (ti<=tj): gram via MFMA,
// fused loss epilogue, block reduce, atomicAdd.
__global__ __launch_bounds__(THREADS, 3) void loss_kernel(const ushort* __restrict__ Xb,
                                                          const float* __restrict__ sq,
                                                          const int* __restrict__ labels,
                                                          float* __restrict__ out) {
    __shared__ ushort At[2][TILE * BK];   // 2 x 8 KB
    __shared__ ushort Bt[2][TILE * BK];   // 2 x 8 KB
    __shared__ float bsum[4];

    // T1: bijective XCD swizzle (528 % 8 == 0): same-XCD blocks get
    // consecutive tile ids -> shared A row-panels stay L2-resident.
    const int b0 = blockIdx.x;
    const int b = (b0 & 7) * (NPAIR / 8) + (b0 >> 3);

    // decode upper-triangular (ti, tj), ti <= tj
    int ti = 0, rem = b;
    while (rem >= NT - ti) { rem -= NT - ti; ++ti; }
    const int tj = ti + rem;

    const int t = threadIdx.x;
    const int lane = t & 63;
    const int wave = t >> 6;      // 0..3
    const int wr = wave >> 1;     // 0..1 : 64-row band of A
    const int wc = wave & 1;      // 0..1 : 64-col band of B
    const int fr = lane & 15;
    const int kg = lane >> 4;

    // Staging (BK=32: 4 x 16B chunks/row). Thread t -> linear LDS bytes
    // [t*16, t*16+16): row sr = t>>2, chunk t&3. T2 swizzle via pre-swizzled
    // global source (rule #21): source chunk = (t&3) ^ ((row>>1)&3).
    const int sr = t >> 2;                            // 0..63
    const int sc = ((t & 3) ^ ((t >> 3) & 3)) * 8;    // swizzled src elem offset
    const ushort* gA = Xb + (size_t)(ti * TILE + sr) * DIM + sc;
    const ushort* gB = Xb + (size_t)(tj * TILE + sr) * DIM + sc;

    // Read-side swizzled chunk: kg ^ ((row>>1)&3), row&7 determined by fr.
    const int swz = (kg ^ ((fr >> 1) & 3)) * 8;

    // Diagonal blocks: wave (1,0) covers rows 64..127 x cols 0..63 -> fully
    // below diagonal, all its outputs masked. Skip compute (keep stage+sync).
    const bool skipw = (ti == tj) && (wr == 1) && (wc == 0);

    f32x4 acc[4][4] = {};

#define STAGE(buf, kt) do {                                                  \
        const int _ko = (kt) * BK;                                           \
        gload_lds16(gA + _ko,                    &At[buf][t * 8]);           \
        gload_lds16(gA + (size_t)64 * DIM + _ko, &At[buf][t * 8 + 64 * BK]); \
        gload_lds16(gB + _ko,                    &Bt[buf][t * 8]);           \
        gload_lds16(gB + (size_t)64 * DIM + _ko, &Bt[buf][t * 8 + 64 * BK]); \
    } while (0)

    int cur = 0;
    STAGE(0, 0);
    __syncthreads();   // drain prologue stage

    for (int kt = 0; kt < KSTEPS; ++kt) {
        if (kt + 1 < KSTEPS) STAGE(cur ^ 1, kt + 1);   // prefetch next tile
        if (!skipw) {
            bf16x8 af[4], bv[4];
#pragma unroll
            for (int m = 0; m < 4; ++m)
                af[m] = *(const bf16x8*)&At[cur][(wr * 64 + m * 16 + fr) * BK + swz];
#pragma unroll
            for (int n = 0; n < 4; ++n)
                bv[n] = *(const bf16x8*)&Bt[cur][(wc * 64 + n * 16 + fr) * BK + swz];
#pragma unroll
            for (int m = 0; m < 4; ++m)
#pragma unroll
                for (int n = 0; n < 4; ++n)
                    acc[m][n] = __builtin_amdgcn_mfma_f32_16x16x32_bf16(
                        af[m], bv[n], acc[m][n], 0, 0, 0);
        }
        __syncthreads();   // prefetch complete + all reads of cur done
        cur ^= 1;
    }
#undef STAGE

    // epilogue: C/D layout col = lane&15 (=fr), row = kg*4 + q  [m89/m91]
    int gi[16]; float sqi[16]; int li[16];
#pragma unroll
    for (int m = 0; m < 4; ++m)
#pragma unroll
        for (int q = 0; q < 4; ++q) {
            const int i = ti * TILE + wr * 64 + m * 16 + kg * 4 + q;
            gi[m * 4 + q] = i;
            sqi[m * 4 + q] = sq[i];
            li[m * 4 + q] = labels[i];
        }
    int gj[4]; float sqj[4]; int lj[4];
#pragma unroll
    for (int n = 0; n < 4; ++n) {
        const int j = tj * TILE + wc * 64 + n * 16 + fr;
        gj[n] = j;
        sqj[n] = sq[j];
        lj[n] = labels[j];
    }

    const float coeff = 2047.0f;                        // N/2 - 1
    const float inva = 1.0f / (2.0f * 4096.0f * 0.04f); // 1/327.68
    const float invb = 1.0f / (2.0f * 4096.0f);         // 1/8192
    const float lc1 = -5.792037522411088f;              // ln(inva)
    const float lc2 = -9.010913347279289f;              // ln(invb)
    const bool diag = (ti == tj);

    float lsum = 0.0f;
#pragma unroll
    for (int m = 0; m < 4; ++m)
#pragma unroll
        for (int n = 0; n < 4; ++n)
#pragma unroll
            for (int q = 0; q < 4; ++q) {
                const int ii = m * 4 + q;
                const float g = acc[m][n][q];
                float d2 = sqi[ii] + sqj[n] - 2.0f * g;
                d2 = fmaxf(d2, 1e-12f);
                const bool same = (li[ii] == lj[n]);
                const float inv = same ? inva : invb;
                const float lc  = same ? lc1 : lc2;
                const float sgn = same ? -1.0f : 1.0f;
                const float p = sgn * (coeff * (__logf(d2) + lc) - 0.5f * d2 * inv);
                const bool inc = diag ? (gi[ii] < gj[n]) : true;
                lsum += inc ? p : 0.0f;
            }

    // block reduce + one atomic per block
#pragma unroll
    for (int off = 32; off > 0; off >>= 1) lsum += __shfl_down(lsum, off);
    if (lane == 0) bsum[wave] = lsum;
    __syncthreads();
    if (t == 0) atomicAdd(out, bsum[0] + bsum[1] + bsum[2] + bsum[3]);
}

extern "C" void kernel_launch(void* const* d_in, const int* in_sizes, int n_in,
                              void* d_out, int out_size, void* d_ws, size_t ws_size,
                              hipStream_t stream) {
    const float* X = (const float*)d_in[0];
    const int* labels = (const int*)d_in[1];
    float* out = (float*)d_out;
    ushort* Xb = (ushort*)d_ws;                                   // 8 MB bf16
    float* sq = (float*)((char*)d_ws + (size_t)NPTS * DIM * 2);   // 16 KB

    hipMemsetAsync(d_out, 0, sizeof(float), stream);
    prep_kernel<<<NPTS, 256, 0, stream>>>(X, Xb, sq);
    loss_kernel<<<NPAIR, THREADS, 0, stream>>>(Xb, sq, labels, out);
}

// Round 4
// 94.638 us; speedup vs baseline: 1.2200x; 1.0698x over previous
//
#include <hip/hip_runtime.h>
#include <hip/hip_bf16.h>
#include <stdint.h>

// MetricLearningLoss: N=4096 points, D=1024, fp32 inputs, int labels.
// loss = sum_{i<j} [ same: -coeff*log(a)+0.5a ; diff: coeff*log(b)-0.5b ]
// R4: MX-fp8 (e4m3, unit scales) via mfma_scale_f32_16x16x128_f8f6f4:
// 2x MFMA rate, half LDS/HBM traffic, 8 K-steps (BK=128 fp8 bytes),
// whole 4MB matrix L2-resident per XCD. 128^2 tile, 4 waves x 64x64,
// dbuf prefetch, XOR swizzle (chunk ^= row&7, pre-swizzled source),
// diag-wave skip, fused log epilogue, T1 XCD swizzle.

#define NPTS 4096
#define DIM  1024
#define TILE 128
#define BK   128                      // fp8 bytes (= elems) per row per step
#define KSTEPS (DIM / BK)             // 8
#define NT   (NPTS / TILE)            // 32
#define NPAIR (NT * (NT + 1) / 2)     // 528 = 8 * 66
#define THREADS 256

typedef __attribute__((ext_vector_type(4))) float f32x4;
typedef __attribute__((ext_vector_type(4))) int   i32x4;
typedef __attribute__((ext_vector_type(8))) int   i32x8;

__device__ __forceinline__ void gload_lds16(const void* g, void* l) {
    __builtin_amdgcn_global_load_lds(
        (const __attribute__((address_space(1))) void*)g,
        (__attribute__((address_space(3))) void*)l, 16, 0, 0);
}

// Kernel 1: fp32 -> fp8 e4m3 (OCP, native gfx950 cvt) + per-row sum of
// squares in fp32 (exact norms; only the gram term is quantized).
__global__ __launch_bounds__(256) void prep_kernel(const float* __restrict__ X,
                                                   uint8_t* __restrict__ Xf8,
                                                   float* __restrict__ sq) {
    const int row = blockIdx.x;
    const int t = threadIdx.x;
    const float4 v = reinterpret_cast<const float4*>(X + (size_t)row * DIM)[t];
    float s = v.x * v.x + v.y * v.y + v.z * v.z + v.w * v.w;
    int w = __builtin_amdgcn_cvt_pk_fp8_f32(v.x, v.y, 0, false);
    w = __builtin_amdgcn_cvt_pk_fp8_f32(v.z, v.w, w, true);
    reinterpret_cast<int*>(Xf8 + (size_t)row * DIM)[t] = w;
#pragma unroll
    for (int off = 32; off > 0; off >>= 1) s += __shfl_down(s, off);
    __shared__ float ws[4];
    const int lane = t & 63, wv = t >> 6;
    if (lane == 0) ws[wv] = s;
    __syncthreads();
    if (t == 0) sq[row] = ws[0] + ws[1] + ws[2] + ws[3];
}

// Kernel 2: per upper-triangular 128x128 tile pair (ti<=tj): gram via
// MX-fp8 MFMA (scales = 1.0), fused loss epilogue, block reduce, atomicAdd.
__global__ __launch_bounds__(THREADS, 2) void loss_kernel(const uint8_t* __restrict__ Xf8,
                                                          const float* __restrict__ sq,
                                                          const int* __restrict__ labels,
                                                          float* __restrict__ out) {
    __shared__ __align__(16) uint8_t At[2][TILE * BK];   // 2 x 16 KB
    __shared__ __align__(16) uint8_t Bt[2][TILE * BK];   // 2 x 16 KB
    __shared__ float bsum[4];

    // T1: bijective XCD swizzle (528 % 8 == 0).
    const int b0 = blockIdx.x;
    const int b = (b0 & 7) * (NPAIR / 8) + (b0 >> 3);

    // decode upper-triangular (ti, tj), ti <= tj
    int ti = 0, rem = b;
    while (rem >= NT - ti) { rem -= NT - ti; ++ti; }
    const int tj = ti + rem;

    const int t = threadIdx.x;
    const int lane = t & 63;
    const int wave = t >> 6;      // 0..3
    const int wr = wave >> 1;     // 0..1 : 64-row band of A
    const int wc = wave & 1;      // 0..1 : 64-col band of B
    const int fr = lane & 15;
    const int kg = lane >> 4;

    // Staging: per tile per step = 16 KB = 1024 x 16B chunks; 4 insts x 256
    // threads. Chunk p = i*256+t -> row p>>3, chunk p&7; T2 swizzle via
    // pre-swizzled source (rule #21): src chunk = (p&7) ^ (row&7).
    size_t srcA[4], srcB[4];
    int ldst[4];
#pragma unroll
    for (int i = 0; i < 4; ++i) {
        const int p = i * 256 + t;
        const int row = p >> 3;
        const int sc = ((p & 7) ^ (row & 7)) << 4;
        srcA[i] = (size_t)(ti * TILE + row) * DIM + sc;
        srcB[i] = (size_t)(tj * TILE + row) * DIM + sc;
        ldst[i] = p << 4;
    }

    // Read-side swizzled chunk offsets (row&7 == fr&7 for all frags since
    // frag row = wr*64 + m*16 + fr). Lane reads k-bytes [32kg, 32kg+32):
    // chunks 2kg, 2kg+1, each XOR'd -> 8 lanes per chunk = bank-uniform.
    const int swz0 = (((kg << 1) ^ (fr & 7)) << 4);
    const int swz1 = swz0 ^ 16;
    const int rbA = (wr * 64 + fr) * BK;
    const int rbB = (wc * 64 + fr) * BK;

    // Diagonal blocks: wave (1,0) fully below diagonal -> skip compute.
    const bool skipw = (ti == tj) && (wr == 1) && (wc == 0);

    f32x4 acc[4][4] = {};

#define STAGE(buf, kt) do {                                            \
        const int _ko = (kt) * BK;                                     \
        _Pragma("unroll")                                              \
        for (int i = 0; i < 4; ++i) {                                  \
            gload_lds16(Xf8 + srcA[i] + _ko, &At[buf][ldst[i]]);       \
            gload_lds16(Xf8 + srcB[i] + _ko, &Bt[buf][ldst[i]]);       \
        }                                                              \
    } while (0)

    int cur = 0;
    STAGE(0, 0);
    __syncthreads();   // drain prologue stage

    for (int kt = 0; kt < KSTEPS; ++kt) {
        if (kt + 1 < KSTEPS) STAGE(cur ^ 1, kt + 1);   // prefetch next tile
        if (!skipw) {
            i32x8 af[4], bv[4];
#pragma unroll
            for (int m = 0; m < 4; ++m) {
                const i32x4 lo = *(const i32x4*)&At[cur][rbA + m * 16 * BK + swz0];
                const i32x4 hi = *(const i32x4*)&At[cur][rbA + m * 16 * BK + swz1];
                af[m][0] = lo[0]; af[m][1] = lo[1]; af[m][2] = lo[2]; af[m][3] = lo[3];
                af[m][4] = hi[0]; af[m][5] = hi[1]; af[m][6] = hi[2]; af[m][7] = hi[3];
            }
#pragma unroll
            for (int n = 0; n < 4; ++n) {
                const i32x4 lo = *(const i32x4*)&Bt[cur][rbB + n * 16 * BK + swz0];
                const i32x4 hi = *(const i32x4*)&Bt[cur][rbB + n * 16 * BK + swz1];
                bv[n][0] = lo[0]; bv[n][1] = lo[1]; bv[n][2] = lo[2]; bv[n][3] = lo[3];
                bv[n][4] = hi[0]; bv[n][5] = hi[1]; bv[n][6] = hi[2]; bv[n][7] = hi[3];
            }
#pragma unroll
            for (int m = 0; m < 4; ++m)
#pragma unroll
                for (int n = 0; n < 4; ++n)
                    acc[m][n] = __builtin_amdgcn_mfma_scale_f32_16x16x128_f8f6f4(
                        af[m], bv[n], acc[m][n],
                        0 /*A=fp8*/, 0 /*B=fp8*/,
                        0, 0x7f7f7f7f,   // scale A = 2^0
                        0, 0x7f7f7f7f);  // scale B = 2^0
        }
        __syncthreads();   // prefetch complete + all reads of cur done
        cur ^= 1;
    }
#undef STAGE

    // epilogue: C/D layout col = lane&15 (=fr), row = kg*4 + q  [m89/m91;
    // shape-determined, dtype-independent per m121-m128]
    int gi[16]; float sqi[16]; int li[16];
#pragma unroll
    for (int m = 0; m < 4; ++m)
#pragma unroll
        for (int q = 0; q < 4; ++q) {
            const int i = ti * TILE + wr * 64 + m * 16 + kg * 4 + q;
            gi[m * 4 + q] = i;
            sqi[m * 4 + q] = sq[i];
            li[m * 4 + q] = labels[i];
        }
    int gj[4]; float sqj[4]; int lj[4];
#pragma unroll
    for (int n = 0; n < 4; ++n) {
        const int j = tj * TILE + wc * 64 + n * 16 + fr;
        gj[n] = j;
        sqj[n] = sq[j];
        lj[n] = labels[j];
    }

    const float coeff = 2047.0f;                        // N/2 - 1
    const float inva = 1.0f / (2.0f * 4096.0f * 0.04f); // 1/327.68
    const float invb = 1.0f / (2.0f * 4096.0f);         // 1/8192
    const float lc1 = -5.792037522411088f;              // ln(inva)
    const float lc2 = -9.010913347279289f;              // ln(invb)
    const bool diag = (ti == tj);

    float lsum = 0.0f;
#pragma unroll
    for (int m = 0; m < 4; ++m)
#pragma unroll
        for (int n = 0; n < 4; ++n)
#pragma unroll
            for (int q = 0; q < 4; ++q) {
                const int ii = m * 4 + q;
                const float g = acc[m][n][q];
                float d2 = sqi[ii] + sqj[n] - 2.0f * g;
                d2 = fmaxf(d2, 1e-12f);
                const bool same = (li[ii] == lj[n]);
                const float inv = same ? inva : invb;
                const float lc  = same ? lc1 : lc2;
                const float sgn = same ? -1.0f : 1.0f;
                const float p = sgn * (coeff * (__logf(d2) + lc) - 0.5f * d2 * inv);
                const bool inc = diag ? (gi[ii] < gj[n]) : true;
                lsum += inc ? p : 0.0f;
            }

    // block reduce + one atomic per block
#pragma unroll
    for (int off = 32; off > 0; off >>= 1) lsum += __shfl_down(lsum, off);
    if (lane == 0) bsum[wave] = lsum;
    __syncthreads();
    if (t == 0) atomicAdd(out, bsum[0] + bsum[1] + bsum[2] + bsum[3]);
}

extern "C" void kernel_launch(void* const* d_in, const int* in_sizes, int n_in,
                              void* d_out, int out_size, void* d_ws, size_t ws_size,
                              hipStream_t stream) {
    const float* X = (const float*)d_in[0];
    const int* labels = (const int*)d_in[1];
    float* out = (float*)d_out;
    uint8_t* Xf8 = (uint8_t*)d_ws;                                  // 4 MB fp8
    float* sq = (float*)((char*)d_ws + (size_t)NPTS * DIM);         // 16 KB

    hipMemsetAsync(d_out, 0, sizeof(float), stream);
    prep_kernel<<<NPTS, 256, 0, stream>>>(X, Xf8, sq);
    loss_kernel<<<NPAIR, THREADS, 0, stream>>>(Xf8, sq, labels, out);
}